// Round 1
// 214.612 us; speedup vs baseline: 1.0212x; 1.0212x over previous
//
#include <hip/hip_runtime.h>

// int8 quantized conv2d 3x3 s1 p1. B=32 Cin=128 H=W=56 Cout=256.
// Implicit GEMM, counted-vmcnt 3-buffer pipelined MFMA i32_16x16x64_i8,
// 2 MFMA phases/chunk + setprio, XCD-swizzled blocks.

#define B_    32
#define CIN   128
#define H_    56
#define W_    56
#define COUT  256
#define HP    58
#define WP    58
#define HWP   (H_*W_)        // 3136
#define NPIX  (B_*HWP)       // 100352
#define NCHUNK 18            // K=1152 / 64
#define ACHUNK 16384         // A bytes per chunk = 256co * 64B

typedef int int4v __attribute__((ext_vector_type(4)));

__device__ __forceinline__ void gld_lds16(const void* g, void* l) {
    __builtin_amdgcn_global_load_lds(
        (const __attribute__((address_space(1))) unsigned int*)g,
        (__attribute__((address_space(3))) unsigned int*)l, 16, 0, 0);
}

// ---------------- fused amax over x and w ----------------
__global__ __launch_bounds__(256) void amax_kernel(const float4* __restrict__ x, long n4x,
                                                   const float4* __restrict__ wt, long n4w,
                                                   unsigned* __restrict__ scales) {
    const float4* p; long n4; unsigned* slot; long start, stride;
    if (blockIdx.x < 2048) {
        p = x; n4 = n4x; slot = scales;
        start = (long)blockIdx.x * 256 + threadIdx.x; stride = 2048L * 256;
    } else {
        p = wt; n4 = n4w; slot = scales + 1;
        start = (long)(blockIdx.x - 2048) * 256 + threadIdx.x; stride = 128L * 256;
    }
    float m = 0.f;
    for (long i = start; i < n4; i += stride) {
        float4 v = p[i];
        m = fmaxf(m, fmaxf(fmaxf(fabsf(v.x), fabsf(v.y)), fmaxf(fabsf(v.z), fabsf(v.w))));
    }
    __shared__ float red[256];
    red[threadIdx.x] = m; __syncthreads();
    for (int s = 128; s > 0; s >>= 1) {
        if (threadIdx.x < s) red[threadIdx.x] = fmaxf(red[threadIdx.x], red[threadIdx.x + s]);
        __syncthreads();
    }
    if (threadIdx.x == 0) atomicMax(slot, __float_as_uint(red[0]));  // all >=0
}

// ---------------- quantize x: NCHW f32 -> padded NHWC int8 (+ border zeroing) ----------------
__global__ __launch_bounds__(256) void quant_x_kernel(const float* __restrict__ x,
        const unsigned* __restrict__ scales, signed char* __restrict__ xq) {
    const int bh = blockIdx.x;
    const int b = bh / H_, h = bh % H_;
    const float sx = 127.0f / __uint_as_float(scales[0]);
    __shared__ int ldsq[W_ * 33];
    const int tid = threadIdx.x;

    // ---- border padding (replaces pad_zero kernel); disjoint rows per block ----
    int4 z; z.x = 0; z.y = 0; z.z = 0; z.w = 0;
    int4* prow = (int4*)(xq + ((long)b * HP + h + 1) * WP * CIN);
    if (tid < 8) prow[tid] = z;                       // col 0 of padded row h+1
    else if (tid < 16) prow[456 + tid - 8] = z;       // col 57 (57*8=456)
    if (h == 0) {
        int4* r0 = (int4*)(xq + (long)b * HP * WP * CIN);
        for (int i = tid; i < 464; i += 256) r0[i] = z;       // padded row 0
    } else if (h == H_ - 1) {
        int4* rt = (int4*)(xq + ((long)b * HP + 57) * WP * CIN);
        for (int i = tid; i < 464; i += 256) rt[i] = z;       // padded row 57
    }

    const int w = tid & 63;
    const int chi = tid >> 6;   // 0..3
    if (w < W_) {
        const float* xb = x + (long)b * CIN * HWP + h * W_ + w;
#pragma unroll
        for (int it = 0; it < 8; ++it) {
            const int c4 = it * 4 + chi;     // 0..31
            int pk = 0;
#pragma unroll
            for (int u = 0; u < 4; ++u) {
                float v = xb[(long)(c4 * 4 + u) * HWP];
                float q = fminf(127.f, fmaxf(-127.f, rintf(v * sx)));
                pk |= ((int)q & 0xff) << (u * 8);
            }
            ldsq[w * 33 + c4] = pk;
        }
    }
    __syncthreads();
    int4* dst = (int4*)(xq + (((long)b * HP + h + 1) * WP + 1) * CIN);
    for (int idx = tid; idx < W_ * 8; idx += 256) {
        const int ww = idx >> 3, c16 = idx & 7;
        int4 v;
        v.x = ldsq[ww * 33 + c16 * 4 + 0];
        v.y = ldsq[ww * 33 + c16 * 4 + 1];
        v.z = ldsq[ww * 33 + c16 * 4 + 2];
        v.w = ldsq[ww * 33 + c16 * 4 + 3];
        dst[ww * 8 + c16] = v;
    }
}

// ---------------- quantize w: OIHW f32 -> packed [chunk][g][cout][16] int8 ----------------
__global__ __launch_bounds__(256) void quant_w_kernel(const float* __restrict__ wt,
        const unsigned* __restrict__ scales, signed char* __restrict__ wq) {
    const int id = blockIdx.x * 256 + threadIdx.x;   // 73728 total
    if (id >= COUT * 9 * 32) return;
    const float sw = 127.0f / __uint_as_float(scales[1]);
    const int co = id / 288;
    const int r  = id % 288;
    const int t  = r / 32;    // tap
    const int c4 = r % 32;    // ci/4
    int pk = 0;
#pragma unroll
    for (int u = 0; u < 4; ++u) {
        float v = wt[(co * CIN + c4 * 4 + u) * 9 + t];
        float q = fminf(127.f, fmaxf(-127.f, rintf(v * sw)));
        pk |= ((int)q & 0xff) << (u * 8);
    }
    const int k = t * CIN + c4 * 4;
    const int chunk = k >> 6;
    const int off = k & 63;
    // [chunk][g=off>>4][co][16B] -> staging is wave-contiguous
    *(int*)(wq + (long)chunk * ACHUNK + (off >> 4) * 4096 + co * 16 + (off & 15)) = pk;
}

// ---------------- conv: counted-vmcnt pipelined MFMA implicit GEMM ----------------
// block 512 thr = 8 waves; tile 256 co x 128 px; wave tile 64x64.
// LDS: 3 chunk-buffers, K-major As[buf][g][co][16B] (16KB), Bs[buf][g][px][16B] (8KB).
// Schedule per chunk: {vmcnt(3); s_barrier} -> STAGE(c+2) -> phaseA(8 mfma) -> s_barrier
//                     -> phaseB(8 mfma). Next chunk's loads stay in flight across barriers.
__global__ __launch_bounds__(512, 4) void conv_kernel(
        const signed char* __restrict__ xq, const signed char* __restrict__ wq,
        const float* __restrict__ bias, const unsigned* __restrict__ scales,
        float* __restrict__ out) {
    __shared__ signed char As[3][16384];
    __shared__ signed char Bs[3][8192];

    const int tid = threadIdx.x;
    const int lane = tid & 63;
    const int wv = tid >> 6;        // 0..7
    const int ln = lane & 15;
    const int g  = lane >> 4;

    const int wco = wv >> 1;        // co quarter 0..3
    const int wpx = wv & 1;         // px half 0..1

    // XCD-aware swizzle: 784 blocks = 8 XCDs * 98 -> contiguous px chunk per XCD
    const int bid = blockIdx.x;
    const int wg  = (bid & 7) * 98 + (bid >> 3);
    const int px_blk = wg * 128;

    // A staging: wave stages insts e=wv*2, wv*2+1 -> contiguous 1KB each (wq repacked)
    const int aoff0 = wv * 2048 + lane * 16;
    const int aoff1 = aoff0 + 1024;

    // B staging: wave does inst wv -> (gB=wv>>1, halfB=wv&1); per-lane fixed px row
    const int gB = wv >> 1, halfB = wv & 1;
    const int pxs = px_blk + halfB * 64 + lane;
    const int bS = pxs / HWP, hwS = pxs % HWP;
    const int hS = hwS / W_, wS = hwS % W_;
    const signed char* srcB = xq + ((bS * HP + hS) * WP + wS) * CIN + gB * 16;
    const int ldsB = gB * 2048 + halfB * 1024 + lane * 16;

#define STAGE(c) { \
    const int tap_ = (c) >> 1; \
    const int toff_ = ((tap_ / 3) * WP + (tap_ % 3)) * CIN + ((c) & 1) * 64; \
    const int bf_ = (c) % 3; \
    gld_lds16(wq + (c) * ACHUNK + aoff0, &As[bf_][aoff0]); \
    gld_lds16(wq + (c) * ACHUNK + aoff1, &As[bf_][aoff1]); \
    gld_lds16(srcB + toff_, &Bs[bf_][ldsB]); }

#define LDA_(i) (*(const int4v*)&As[buf][g * 4096 + (wco * 64 + (i) * 16 + ln) * 16])
#define LDB_(j) (*(const int4v*)&Bs[buf][g * 2048 + (wpx * 64 + (j) * 16 + ln) * 16])
#define MM(i, j, A, Bv) acc[i][j] = __builtin_amdgcn_mfma_i32_16x16x64_i8(A, Bv, acc[i][j], 0, 0, 0)

#define CHUNK(c, VM) { \
    const int buf = (c) % 3; \
    asm volatile("s_waitcnt vmcnt(" #VM ")\n\ts_barrier" ::: "memory"); \
    __builtin_amdgcn_sched_barrier(0); \
    if ((c) + 2 < NCHUNK) STAGE((c) + 2); \
    int4v Bf0 = LDB_(0), Bf1 = LDB_(1), Bf2 = LDB_(2), Bf3 = LDB_(3); \
    int4v Af0 = LDA_(0), Af1 = LDA_(1); \
    __builtin_amdgcn_s_setprio(1); \
    MM(0, 0, Af0, Bf0); MM(0, 1, Af0, Bf1); MM(0, 2, Af0, Bf2); MM(0, 3, Af0, Bf3); \
    MM(1, 0, Af1, Bf0); MM(1, 1, Af1, Bf1); MM(1, 2, Af1, Bf2); MM(1, 3, Af1, Bf3); \
    __builtin_amdgcn_s_setprio(0); \
    asm volatile("s_barrier" ::: "memory"); \
    __builtin_amdgcn_sched_barrier(0); \
    int4v Af2 = LDA_(2), Af3 = LDA_(3); \
    __builtin_amdgcn_s_setprio(1); \
    MM(2, 0, Af2, Bf0); MM(2, 1, Af2, Bf1); MM(2, 2, Af2, Bf2); MM(2, 3, Af2, Bf3); \
    MM(3, 0, Af3, Bf0); MM(3, 1, Af3, Bf1); MM(3, 2, Af3, Bf2); MM(3, 3, Af3, Bf3); \
    __builtin_amdgcn_s_setprio(0); }

    int4v acc[4][4] = {};
    STAGE(0);
    STAGE(1);
    CHUNK(0, 3)  CHUNK(1, 3)  CHUNK(2, 3)  CHUNK(3, 3)  CHUNK(4, 3)  CHUNK(5, 3)
    CHUNK(6, 3)  CHUNK(7, 3)  CHUNK(8, 3)  CHUNK(9, 3)  CHUNK(10, 3) CHUNK(11, 3)
    CHUNK(12, 3) CHUNK(13, 3) CHUNK(14, 3) CHUNK(15, 3) CHUNK(16, 3) CHUNK(17, 0)
#undef CHUNK
#undef MM
#undef LDA_
#undef LDB_
#undef STAGE

    const float ax = __uint_as_float(scales[0]);
    const float aw = __uint_as_float(scales[1]);
    const float inv = 1.0f / ((127.0f / ax) * (127.0f / aw));

    // D 16x16: col(=px) = lane&15, row(=co) = g*4 + r
#pragma unroll
    for (int i = 0; i < 4; ++i) {
        const int co = wco * 64 + i * 16 + g * 4;
#pragma unroll
        for (int r = 0; r < 4; ++r) {
            const float bsv = bias[co + r];
#pragma unroll
            for (int j = 0; j < 4; ++j) {
                const int px = px_blk + wpx * 64 + j * 16 + ln;
                const int b = px / HWP, hw = px % HWP;
                out[((long)(b * COUT + co + r)) * HWP + hw] = (float)acc[i][j][r] * inv + bsv;
            }
        }
    }
}

extern "C" void kernel_launch(void* const* d_in, const int* in_sizes, int n_in,
                              void* d_out, int out_size, void* d_ws, size_t ws_size,
                              hipStream_t stream) {
    const float* x  = (const float*)d_in[0];
    const float* wt = (const float*)d_in[1];
    const float* bs = (const float*)d_in[2];
    float* out = (float*)d_out;

    unsigned* scales = (unsigned*)d_ws;                  // [0]=amax_x, [1]=amax_w (bits)
    const size_t XQ_OFF   = 256;
    const size_t XQ_BYTES = (size_t)B_ * HP * WP * CIN;  // 13,778,944
    signed char* xq = (signed char*)d_ws + XQ_OFF;
    signed char* wq = xq + XQ_BYTES;

    hipMemsetAsync(d_ws, 0, 8, stream);                  // zero the two amax slots

    const long n4x = (long)B_ * CIN * H_ * W_ / 4;
    const long n4w = (long)COUT * CIN * 9 / 4;
    amax_kernel<<<2176, 256, 0, stream>>>((const float4*)x, n4x, (const float4*)wt, n4w, scales);

    quant_x_kernel<<<B_ * H_, 256, 0, stream>>>(x, scales, xq);
    quant_w_kernel<<<(COUT * 9 * 32 + 255) / 256, 256, 0, stream>>>(wt, scales, wq);

    conv_kernel<<<NPIX / 128, 512, 0, stream>>>(xq, wq, bs, scales, out);
}

// Round 2
// 214.516 us; speedup vs baseline: 1.0217x; 1.0004x over previous
//
#include <hip/hip_runtime.h>

// int8 quantized conv2d 3x3 s1 p1. B=32 Cin=128 H=W=56 Cout=256.
// Implicit GEMM, counted-vmcnt 3-buffer ring, 1 barrier/chunk, XCD-swizzled,
// LDS-transposed float4 epilogue.

#define B_    32
#define CIN   128
#define H_    56
#define W_    56
#define COUT  256
#define HP    58
#define WP    58
#define HWP   (H_*W_)        // 3136
#define NPIX  (B_*HWP)       // 100352
#define NCHUNK 18            // K=1152 / 64
#define ACHUNK 16384         // A bytes per chunk = 256co * 64B

typedef int int4v __attribute__((ext_vector_type(4)));

__device__ __forceinline__ void gld_lds16(const void* g, void* l) {
    __builtin_amdgcn_global_load_lds(
        (const __attribute__((address_space(1))) unsigned int*)g,
        (__attribute__((address_space(3))) unsigned int*)l, 16, 0, 0);
}

// ---------------- fused amax over x and w ----------------
__global__ __launch_bounds__(256) void amax_kernel(const float4* __restrict__ x, long n4x,
                                                   const float4* __restrict__ wt, long n4w,
                                                   unsigned* __restrict__ scales) {
    const float4* p; long n4; unsigned* slot; long start, stride;
    if (blockIdx.x < 2048) {
        p = x; n4 = n4x; slot = scales;
        start = (long)blockIdx.x * 256 + threadIdx.x; stride = 2048L * 256;
    } else {
        p = wt; n4 = n4w; slot = scales + 1;
        start = (long)(blockIdx.x - 2048) * 256 + threadIdx.x; stride = 128L * 256;
    }
    float m = 0.f;
    for (long i = start; i < n4; i += stride) {
        float4 v = p[i];
        m = fmaxf(m, fmaxf(fmaxf(fabsf(v.x), fabsf(v.y)), fmaxf(fabsf(v.z), fabsf(v.w))));
    }
    __shared__ float red[256];
    red[threadIdx.x] = m; __syncthreads();
    for (int s = 128; s > 0; s >>= 1) {
        if (threadIdx.x < s) red[threadIdx.x] = fmaxf(red[threadIdx.x], red[threadIdx.x + s]);
        __syncthreads();
    }
    if (threadIdx.x == 0) atomicMax(slot, __float_as_uint(red[0]));  // all >=0
}

// ---------------- quantize x: NCHW f32 -> padded NHWC int8 (+ border zeroing) ----------------
__global__ __launch_bounds__(256) void quant_x_kernel(const float* __restrict__ x,
        const unsigned* __restrict__ scales, signed char* __restrict__ xq) {
    const int bh = blockIdx.x;
    const int b = bh / H_, h = bh % H_;
    const float sx = 127.0f / __uint_as_float(scales[0]);
    __shared__ int ldsq[W_ * 33];
    const int tid = threadIdx.x;

    // ---- border padding; disjoint rows per block ----
    int4 z; z.x = 0; z.y = 0; z.z = 0; z.w = 0;
    int4* prow = (int4*)(xq + ((long)b * HP + h + 1) * WP * CIN);
    if (tid < 8) prow[tid] = z;                       // col 0 of padded row h+1
    else if (tid < 16) prow[456 + tid - 8] = z;       // col 57 (57*8=456)
    if (h == 0) {
        int4* r0 = (int4*)(xq + (long)b * HP * WP * CIN);
        for (int i = tid; i < 464; i += 256) r0[i] = z;       // padded row 0
    } else if (h == H_ - 1) {
        int4* rt = (int4*)(xq + ((long)b * HP + 57) * WP * CIN);
        for (int i = tid; i < 464; i += 256) rt[i] = z;       // padded row 57
    }

    const int w = tid & 63;
    const int chi = tid >> 6;   // 0..3
    if (w < W_) {
        const float* xb = x + (long)b * CIN * HWP + h * W_ + w;
#pragma unroll
        for (int it = 0; it < 8; ++it) {
            const int c4 = it * 4 + chi;     // 0..31
            int pk = 0;
#pragma unroll
            for (int u = 0; u < 4; ++u) {
                float v = xb[(long)(c4 * 4 + u) * HWP];
                float q = fminf(127.f, fmaxf(-127.f, rintf(v * sx)));
                pk |= ((int)q & 0xff) << (u * 8);
            }
            ldsq[w * 33 + c4] = pk;
        }
    }
    __syncthreads();
    int4* dst = (int4*)(xq + (((long)b * HP + h + 1) * WP + 1) * CIN);
    for (int idx = tid; idx < W_ * 8; idx += 256) {
        const int ww = idx >> 3, c16 = idx & 7;
        int4 v;
        v.x = ldsq[ww * 33 + c16 * 4 + 0];
        v.y = ldsq[ww * 33 + c16 * 4 + 1];
        v.z = ldsq[ww * 33 + c16 * 4 + 2];
        v.w = ldsq[ww * 33 + c16 * 4 + 3];
        dst[ww * 8 + c16] = v;
    }
}

// ---------------- quantize w: OIHW f32 -> packed [chunk][g][cout][16] int8 ----------------
__global__ __launch_bounds__(256) void quant_w_kernel(const float* __restrict__ wt,
        const unsigned* __restrict__ scales, signed char* __restrict__ wq) {
    const int id = blockIdx.x * 256 + threadIdx.x;   // 73728 total
    if (id >= COUT * 9 * 32) return;
    const float sw = 127.0f / __uint_as_float(scales[1]);
    const int co = id / 288;
    const int r  = id % 288;
    const int t  = r / 32;    // tap
    const int c4 = r % 32;    // ci/4
    int pk = 0;
#pragma unroll
    for (int u = 0; u < 4; ++u) {
        float v = wt[(co * CIN + c4 * 4 + u) * 9 + t];
        float q = fminf(127.f, fmaxf(-127.f, rintf(v * sw)));
        pk |= ((int)q & 0xff) << (u * 8);
    }
    const int k = t * CIN + c4 * 4;
    const int chunk = k >> 6;
    const int off = k & 63;
    // [chunk][g=off>>4][co][16B] -> staging is wave-contiguous
    *(int*)(wq + (long)chunk * ACHUNK + (off >> 4) * 4096 + co * 16 + (off & 15)) = pk;
}

// ---------------- conv: counted-vmcnt ring MFMA implicit GEMM ----------------
// block 512 thr = 8 waves; tile 256 co x 128 px; wave tile 64x64.
// LDS: 3-buffer ring, A[buf]=[g][co][16B] 16KB, B[buf]=[g][px][16B] 8KB (72KB total).
// Per chunk: {vmcnt(3); s_barrier} -> STAGE(c+2) -> ds_read 8 frags -> 16 MFMA.
// Epilogue: LDS transpose (stride 130 f32 = 2-way banks) -> float4 stores.
__global__ __launch_bounds__(512, 4) void conv_kernel(
        const signed char* __restrict__ xq, const signed char* __restrict__ wq,
        const float* __restrict__ bias, const unsigned* __restrict__ scales,
        float* __restrict__ out) {
    __shared__ signed char smem[73728];   // A ring 0..49151, B ring 49152..73727

    const int tid = threadIdx.x;
    const int lane = tid & 63;
    const int wv = tid >> 6;        // 0..7
    const int ln = lane & 15;
    const int g  = lane >> 4;

    const int wco = wv >> 1;        // co quarter 0..3
    const int wpx = wv & 1;         // px half 0..1

    // XCD-aware swizzle: 784 blocks = 8 XCDs * 98 -> contiguous px chunk per XCD
    const int bid = blockIdx.x;
    const int wg  = (bid & 7) * 98 + (bid >> 3);
    const int px_blk = wg * 128;

    // A staging: wave stages 2KB contiguous (wq packed [chunk][g][co][16])
    const int aoff0 = wv * 2048 + lane * 16;
    const int aoff1 = aoff0 + 1024;

    // B staging: wave does inst wv -> (gB=wv>>1, halfB=wv&1); per-lane fixed px row
    const int gB = wv >> 1, halfB = wv & 1;
    const int pxs = px_blk + halfB * 64 + lane;
    const int bS = pxs / HWP, hwS = pxs % HWP;
    const int hS = hwS / W_, wS = hwS % W_;
    const signed char* srcB = xq + ((bS * HP + hS) * WP + wS) * CIN + gB * 16;
    const int ldsB = gB * 2048 + halfB * 1024 + lane * 16;

#define STAGE(c) { \
    const int tap_ = (c) >> 1; \
    const int toff_ = ((tap_ / 3) * WP + (tap_ % 3)) * CIN + ((c) & 1) * 64; \
    const int bf_ = (c) % 3; \
    gld_lds16(wq + (c) * ACHUNK + aoff0, &smem[bf_ * 16384 + aoff0]); \
    gld_lds16(wq + (c) * ACHUNK + aoff1, &smem[bf_ * 16384 + aoff1]); \
    gld_lds16(srcB + toff_, &smem[49152 + bf_ * 8192 + ldsB]); }

#define LDA_(i) (*(const int4v*)&smem[buf * 16384 + g * 4096 + (wco * 64 + (i) * 16 + ln) * 16])
#define LDB_(j) (*(const int4v*)&smem[49152 + buf * 8192 + g * 2048 + (wpx * 64 + (j) * 16 + ln) * 16])
#define MM(i, j, A, Bv) acc[i][j] = __builtin_amdgcn_mfma_i32_16x16x64_i8(A, Bv, acc[i][j], 0, 0, 0)

#define CHUNK(c, VM) { \
    const int buf = (c) % 3; \
    asm volatile("s_waitcnt vmcnt(" #VM ")\n\ts_barrier" ::: "memory"); \
    if ((c) + 2 < NCHUNK) STAGE((c) + 2); \
    int4v Bf0 = LDB_(0), Bf1 = LDB_(1), Bf2 = LDB_(2), Bf3 = LDB_(3); \
    int4v Af0 = LDA_(0), Af1 = LDA_(1), Af2 = LDA_(2), Af3 = LDA_(3); \
    __builtin_amdgcn_s_setprio(1); \
    MM(0, 0, Af0, Bf0); MM(0, 1, Af0, Bf1); MM(0, 2, Af0, Bf2); MM(0, 3, Af0, Bf3); \
    MM(1, 0, Af1, Bf0); MM(1, 1, Af1, Bf1); MM(1, 2, Af1, Bf2); MM(1, 3, Af1, Bf3); \
    MM(2, 0, Af2, Bf0); MM(2, 1, Af2, Bf1); MM(2, 2, Af2, Bf2); MM(2, 3, Af2, Bf3); \
    MM(3, 0, Af3, Bf0); MM(3, 1, Af3, Bf1); MM(3, 2, Af3, Bf2); MM(3, 3, Af3, Bf3); \
    __builtin_amdgcn_s_setprio(0); }

    int4v acc[4][4] = {};
    STAGE(0);
    STAGE(1);
    CHUNK(0, 3)  CHUNK(1, 3)  CHUNK(2, 3)  CHUNK(3, 3)  CHUNK(4, 3)  CHUNK(5, 3)
    CHUNK(6, 3)  CHUNK(7, 3)  CHUNK(8, 3)  CHUNK(9, 3)  CHUNK(10, 3) CHUNK(11, 3)
    CHUNK(12, 3) CHUNK(13, 3) CHUNK(14, 3) CHUNK(15, 3) CHUNK(16, 3) CHUNK(17, 0)
#undef CHUNK
#undef MM
#undef LDA_
#undef LDB_
#undef STAGE

    const float ax = __uint_as_float(scales[0]);
    const float aw = __uint_as_float(scales[1]);
    const float inv = 1.0f / ((127.0f / ax) * (127.0f / aw));

    // -------- epilogue: LDS transpose -> float4 stores --------
    // acc element (i,j,r): co = wco*64 + i*16 + g*4 + r, px = px_blk + wpx*64 + j*16 + ln
    __syncthreads();                       // all LDS frag reads consumed (lgkm before MFMA)
    float* ldsT = (float*)smem;            // [128 co rows][stride 130 floats] = 66560 B

    const int c4 = tid & 31;               // float4 column
    const int rsel = tid >> 5;             // 0..15
    const int px4 = px_blk + c4 * 4;
    const int bb = px4 / HWP, hw = px4 - bb * HWP;
    float4* outb = (float4*)(out + (long)bb * COUT * HWP + hw);

#pragma unroll
    for (int p = 0; p < 2; ++p) {
        if ((wv >> 2) == p) {              // waves owning co half p stage their 64 values
            const int cl0 = (wco & 1) * 64;
#pragma unroll
            for (int i = 0; i < 4; ++i)
#pragma unroll
                for (int r = 0; r < 4; ++r) {
                    const int cl = cl0 + i * 16 + g * 4 + r;
#pragma unroll
                    for (int j = 0; j < 4; ++j)
                        ldsT[cl * 130 + wpx * 64 + j * 16 + ln] = (float)acc[i][j][r] * inv;
                }
        }
        __syncthreads();
#pragma unroll
        for (int it = 0; it < 8; ++it) {
            const int row = it * 16 + rsel;
            const int co = p * 128 + row;
            float4 v = *(float4*)&ldsT[row * 130 + c4 * 4];
            const float bsv = bias[co];
            v.x += bsv; v.y += bsv; v.z += bsv; v.w += bsv;
            outb[(long)co * (HWP / 4)] = v;
        }
        if (p == 0) __syncthreads();
    }
}

extern "C" void kernel_launch(void* const* d_in, const int* in_sizes, int n_in,
                              void* d_out, int out_size, void* d_ws, size_t ws_size,
                              hipStream_t stream) {
    const float* x  = (const float*)d_in[0];
    const float* wt = (const float*)d_in[1];
    const float* bs = (const float*)d_in[2];
    float* out = (float*)d_out;

    unsigned* scales = (unsigned*)d_ws;                  // [0]=amax_x, [1]=amax_w (bits)
    const size_t XQ_OFF   = 256;
    const size_t XQ_BYTES = (size_t)B_ * HP * WP * CIN;  // 13,778,944
    signed char* xq = (signed char*)d_ws + XQ_OFF;
    signed char* wq = xq + XQ_BYTES;

    hipMemsetAsync(d_ws, 0, 8, stream);                  // zero the two amax slots

    const long n4x = (long)B_ * CIN * H_ * W_ / 4;
    const long n4w = (long)COUT * CIN * 9 / 4;
    amax_kernel<<<2176, 256, 0, stream>>>((const float4*)x, n4x, (const float4*)wt, n4w, scales);

    quant_x_kernel<<<B_ * H_, 256, 0, stream>>>(x, scales, xq);
    quant_w_kernel<<<(COUT * 9 * 32 + 255) / 256, 256, 0, stream>>>(wt, scales, wq);

    conv_kernel<<<NPIX / 128, 512, 0, stream>>>(xq, wq, bs, scales, out);
}